// Round 5
// baseline (581.913 us; speedup 1.0000x reference)
//
#include <hip/hip_runtime.h>
#include <hip/hip_bf16.h>

// Problem constants (from reference): N=262144, NS=8, C=32, S=8 -> C/S=4
#define NPTS   262144
#define NSAMP  8
#define NPAIR  (NPTS * NSAMP)           // 2097152
#define EPSV   1e-5f
#define INVCNT (1.0f / (float)NPAIR)
#define GSTAT  2048                      // grid for stat kernels (8 blocks/CU -> 100% occ ceiling)
#define P2ROWS 1024                      // P2 partial rows (2 blocks atomicAdd per row, fits ws header)

typedef __hip_bfloat16 bf16;

template <typename T> __device__ __forceinline__ float cvt(T v);
template <> __device__ __forceinline__ float cvt<float>(float v) { return v; }
template <> __device__ __forceinline__ float cvt<bf16>(bf16 v) { return __bfloat162float(v); }

template <typename T> __device__ __forceinline__ T f2t(float v);
template <> __device__ __forceinline__ float f2t<float>(float v) { return v; }
template <> __device__ __forceinline__ bf16  f2t<bf16>(float v)  { return __float2bfloat16(v); }

// Vectorized 32-element row load (16B chunks). bf16 path unpacks via bit ops
// (bf16->f32 is exact <<16). Addresses are 16B-aligned: rows are 64B/128B.
template <typename T> __device__ __forceinline__ void loadrow32(const T* __restrict__ p, float* out);
template <> __device__ __forceinline__ void loadrow32<float>(const float* __restrict__ p, float* out)
{
    const float4* __restrict__ p4 = (const float4*)p;
#pragma unroll
    for (int b = 0; b < 8; ++b) {
        const float4 v = p4[b];
        out[b * 4 + 0] = v.x; out[b * 4 + 1] = v.y;
        out[b * 4 + 2] = v.z; out[b * 4 + 3] = v.w;
    }
}
template <> __device__ __forceinline__ void loadrow32<bf16>(const bf16* __restrict__ p, float* out)
{
    const uint4* __restrict__ p4 = (const uint4*)p;
#pragma unroll
    for (int b = 0; b < 4; ++b) {
        const uint4 u = p4[b];
        const unsigned int w[4] = {u.x, u.y, u.z, u.w};
#pragma unroll
        for (int m = 0; m < 4; ++m) {
            out[b * 8 + 2 * m + 0] = __uint_as_float(w[m] << 16);
            out[b * 8 + 2 * m + 1] = __uint_as_float(w[m] & 0xFFFF0000u);
        }
    }
}

// ---------------------------------------------------------------------------
// Detector: decide whether float inputs are bf16 (flag=0) or fp32 (flag=1).
// ---------------------------------------------------------------------------
__global__ void k_detect(const unsigned int* __restrict__ xw, int* __restrict__ flag)
{
    if (threadIdx.x == 0 && blockIdx.x == 0) {
        int cnt = 0;
        for (int i = 0; i < 256; ++i) {
            const unsigned int w = xw[i];
            const unsigned int e = (w >> 7) & 0xFF;   // exponent of low bf16
            if (e >= 110 && e <= 132) ++cnt;
        }
        flag[0] = (cnt >= 128) ? 0 : 1;
    }
}

// ---------------------------------------------------------------------------
// K1: q,k,v = x @ W.T + b   (fp32 out). blockIdx.y in {0,1,2} selects WHICH
// output this block computes, so a lane holds only 32 weight floats (round-4
// lesson: 96 floats under a 128-VGPR cap got demoted to scratch -> 3.2 GB of
// L2 scratch reads -> 100 us). No LDS at all: lanes 0..31 of a half-wave read
// the SAME x row as 16B vector loads (TA/L1 broadcast); x stays L2/L3-hot
// across the 3 y-slices. Inner loop = pure register FMA.
// y==0 slice also zero-inits the P2 atomic partial rows.
// ---------------------------------------------------------------------------
template <typename T>
__global__ __launch_bounds__(256, 4) void k_qkv(
    const T* __restrict__ x,
    const T* __restrict__ Wq, const T* __restrict__ bq,
    const T* __restrict__ Wk, const T* __restrict__ bk,
    const T* __restrict__ Wv, const T* __restrict__ bv,
    float* __restrict__ q, float* __restrict__ k, float* __restrict__ v,
    float* __restrict__ P2z,
    const int* __restrict__ flag, const int want)
{
    if (flag[0] != want) return;
    const int t = threadIdx.x;
    const int which = blockIdx.y;
    if (which == 0 && t < 32) P2z[blockIdx.x * 32 + t] = 0.f;
    const T* __restrict__ W; const T* __restrict__ b; float* __restrict__ o;
    if (which == 0)      { W = Wq; b = bq; o = q; }
    else if (which == 1) { W = Wk; b = bk; o = k; }
    else                 { W = Wv; b = bv; o = v; }
    const int c = t & 31, pi = t >> 5;
    float w[32];
    loadrow32<T>(W + c * 32, w);          // one-time: lane c holds row c (32 VGPR)
    const float bias = cvt<T>(b[c]);
    const int base0 = blockIdx.x * 128;   // 128 points per block
    for (int it = 0; it < 16; ++it) {
        const int ip = base0 + it * 8 + pi;
        float xr[32];
        loadrow32<T>(x + ip * 32, xr);    // broadcast within half-wave
        float a = bias;
#pragma unroll
        for (int j = 0; j < 32; ++j) a += w[j] * xr[j];
        o[ip * 32 + c] = a;
    }
}

// ---------------------------------------------------------------------------
// K2: pr1 = (p[idx]-p) @ Wp1.T + bp1 (store), BN1 partial sums (3 ch, pad 8)
// Partial row layout: [0..2] sum, [8..10] sumsq, stride 16. 2048 rows.
// ---------------------------------------------------------------------------
template <typename T>
__global__ __launch_bounds__(256) void k_pr1(
    const T* __restrict__ p, const int* __restrict__ idx,
    const T* __restrict__ Wp1, const T* __restrict__ bp1,
    float* __restrict__ pr1, float* __restrict__ P1,
    const int* __restrict__ flag, const int want)
{
    if (flag[0] != want) return;
    float W[3][3], B[3];
#pragma unroll
    for (int a = 0; a < 3; ++a) {
        B[a] = cvt<T>(bp1[a]);
#pragma unroll
        for (int d = 0; d < 3; ++d) W[a][d] = cvt<T>(Wp1[a * 3 + d]);
    }
    const int t = threadIdx.x;
    const int base = blockIdx.x * 1024;           // 1024 pairs per block
    float s[3] = {0.f, 0.f, 0.f}, ss[3] = {0.f, 0.f, 0.f};
    for (int it = 0; it < 1024; it += 256) {
        const int pid = base + it + t;
        const int i = pid >> 3;
        const int nj = idx[pid];
        const float d0 = cvt<T>(p[nj * 3 + 0]) - cvt<T>(p[i * 3 + 0]);
        const float d1 = cvt<T>(p[nj * 3 + 1]) - cvt<T>(p[i * 3 + 1]);
        const float d2 = cvt<T>(p[nj * 3 + 2]) - cvt<T>(p[i * 3 + 2]);
#pragma unroll
        for (int a = 0; a < 3; ++a) {
            const float r = W[a][0] * d0 + W[a][1] * d1 + W[a][2] * d2 + B[a];
            pr1[pid * 3 + a] = r;
            s[a] += r; ss[a] += r * r;
        }
    }
#pragma unroll
    for (int o = 32; o > 0; o >>= 1) {
#pragma unroll
        for (int a = 0; a < 3; ++a) { s[a] += __shfl_down(s[a], o); ss[a] += __shfl_down(ss[a], o); }
    }
    __shared__ float red[4][16];
    const int wid = t >> 6, lane = t & 63;
    if (lane == 0) {
#pragma unroll
        for (int u = 0; u < 16; ++u) red[wid][u] = 0.f;
#pragma unroll
        for (int a = 0; a < 3; ++a) { red[wid][a] = s[a]; red[wid][8 + a] = ss[a]; }
    }
    __syncthreads();
    if (t < 16) P1[blockIdx.x * 16 + t] = red[0][t] + red[1][t] + red[2][t] + red[3][t];
}

// ---------------------------------------------------------------------------
// Finalize: reduce partial rows -> coef a/c.
// One block PER CHANNEL (grid = NC_), 256 threads grid-stride over rows.
// ---------------------------------------------------------------------------
template <typename T, int NC_, int NP_>
__global__ __launch_bounds__(256) void k_fin(
    const float* __restrict__ P, const int nrows,
    const T* __restrict__ g, const T* __restrict__ b,
    float* __restrict__ A, float* __restrict__ Cc,
    const int* __restrict__ flag, const int want)
{
    if (flag[0] != want) return;
    constexpr int COLS = 2 * NP_;
    const int c = blockIdx.x;           // channel (< NC_)
    const int t = threadIdx.x;
    float s = 0.f, ss = 0.f;
    for (int r = t; r < nrows; r += 256) {
        s  += P[r * COLS + c];
        ss += P[r * COLS + NP_ + c];
    }
#pragma unroll
    for (int o = 32; o > 0; o >>= 1) { s += __shfl_down(s, o); ss += __shfl_down(ss, o); }
    __shared__ float rs[4], rss[4];
    if ((t & 63) == 0) { rs[t >> 6] = s; rss[t >> 6] = ss; }
    __syncthreads();
    if (t == 0) {
        s  = rs[0] + rs[1] + rs[2] + rs[3];
        ss = rss[0] + rss[1] + rss[2] + rss[3];
        const float m = s * INVCNT;
        const float var = ss * INVCNT - m * m;
        const float a = cvt<T>(g[c]) * rsqrtf(var + EPSV);
        A[c]  = a;
        Cc[c] = cvt<T>(b[c]) - a * m;
    }
}

// ---------------------------------------------------------------------------
// K4: BN2 partials over w_pre = k[idx] - q + relu(bn1(pr1)) @ Wp2.T + bp2
// Layout: c = t&31 (channel-parallel), 8 pairs per 256-thread iteration.
// Partial row: [c] sum, [32+c] sumsq, stride 64. 1024 rows; pairs of blocks
// atomicAdd into the same row (rows zeroed by k_qkv y==0 slice).
// ---------------------------------------------------------------------------
template <typename T>
__global__ __launch_bounds__(256) void k_bn2stat(
    const int* __restrict__ idx, const float* __restrict__ pr1,
    const float* __restrict__ q, const float* __restrict__ k,
    const T* __restrict__ Wp2, const T* __restrict__ bp2,
    const float* __restrict__ coef, float* __restrict__ P2,
    const int* __restrict__ flag, const int want)
{
    if (flag[0] != want) return;
    const int t = threadIdx.x;
    const int c = t & 31;
    const float a10 = coef[0], a11 = coef[1], a12 = coef[2];
    const float c10 = coef[8], c11 = coef[9], c12 = coef[10];
    const float w0 = cvt<T>(Wp2[c * 3 + 0]), w1 = cvt<T>(Wp2[c * 3 + 1]), w2 = cvt<T>(Wp2[c * 3 + 2]);
    const float bb = cvt<T>(bp2[c]);
    float s = 0.f, ss = 0.f;
    const int base = blockIdx.x * 1024;           // 1024 pairs per block
    for (int it = 0; it < 1024; it += 8) {
        const int pid = base + it + (t >> 5);
        const int i = pid >> 3;
        const int nj = idx[pid];
        const float h0 = fmaxf(a10 * pr1[pid * 3 + 0] + c10, 0.f);
        const float h1 = fmaxf(a11 * pr1[pid * 3 + 1] + c11, 0.f);
        const float h2 = fmaxf(a12 * pr1[pid * 3 + 2] + c12, 0.f);
        const float pr2 = w0 * h0 + w1 * h1 + w2 * h2 + bb;
        const float wp = k[nj * 32 + c] - q[i * 32 + c] + pr2;
        s += wp; ss += wp * wp;
    }
    s += __shfl_down(s, 32); ss += __shfl_down(ss, 32);
    __shared__ float red[4][64];
    const int wid = t >> 6, lane = t & 63;
    if (lane < 32) { red[wid][lane] = s; red[wid][32 + lane] = ss; }
    __syncthreads();
    if (t < 64) atomicAdd(&P2[(blockIdx.x >> 1) * 64 + t],
                          red[0][t] + red[1][t] + red[2][t] + red[3][t]);
}

// ---------------------------------------------------------------------------
// K6: w1 = relu(bn2(w_pre)) @ Ww1.T + bww1 (store), BN3 partials (4 ch)
// Thread-per-pair. Partial row: [0..3] sum, [4..7] sumsq, stride 8. 2048 rows.
// Also writes h = relu(bn1(pr1)) BACK into pr1 in-place (each pid owned by
// exactly one thread; bn2stat already consumed raw pr1) so k_out can skip BN1.
// ---------------------------------------------------------------------------
template <typename T>
__global__ __launch_bounds__(256, 4) void k_w1(
    const int* __restrict__ idx, float* __restrict__ pr1,
    const float* __restrict__ q, const float* __restrict__ k,
    const T* __restrict__ Wp2, const T* __restrict__ bp2,
    const T* __restrict__ Ww1, const T* __restrict__ bww1,
    const float* __restrict__ coef, float* __restrict__ w1out, float* __restrict__ P3,
    const int* __restrict__ flag, const int want)
{
    if (flag[0] != want) return;
    __shared__ float sWp2[32][3], sbp2[32], sW1[4][32], sb1[4], sa2[32], sc2[32];
    const int t = threadIdx.x;
    if (t < 32) {
        sWp2[t][0] = cvt<T>(Wp2[t * 3 + 0]);
        sWp2[t][1] = cvt<T>(Wp2[t * 3 + 1]);
        sWp2[t][2] = cvt<T>(Wp2[t * 3 + 2]);
        sbp2[t] = cvt<T>(bp2[t]);
        sa2[t] = coef[16 + t];
        sc2[t] = coef[48 + t];
    }
    if (t < 4) sb1[t] = cvt<T>(bww1[t]);
    if (t < 128) sW1[t >> 5][t & 31] = cvt<T>(Ww1[t]);
    __syncthreads();
    const float a10 = coef[0], a11 = coef[1], a12 = coef[2];
    const float c10 = coef[8], c11 = coef[9], c12 = coef[10];
    float s[4] = {0.f, 0.f, 0.f, 0.f}, ss[4] = {0.f, 0.f, 0.f, 0.f};
    const int base = blockIdx.x * 1024;           // 1024 pairs per block
    for (int it = 0; it < 1024; it += 256) {
        const int pid = base + it + t;
        const int i = pid >> 3;
        const int nj = idx[pid];
        const float h0 = fmaxf(a10 * pr1[pid * 3 + 0] + c10, 0.f);
        const float h1 = fmaxf(a11 * pr1[pid * 3 + 1] + c11, 0.f);
        const float h2 = fmaxf(a12 * pr1[pid * 3 + 2] + c12, 0.f);
        pr1[pid * 3 + 0] = h0;          // materialize h for k_out
        pr1[pid * 3 + 1] = h1;
        pr1[pid * 3 + 2] = h2;
        float acc0 = sb1[0], acc1 = sb1[1], acc2 = sb1[2], acc3 = sb1[3];
        const float4* __restrict__ krow = (const float4*)(k + nj * 32);
        const float4* __restrict__ qrow = (const float4*)(q + i * 32);
#pragma unroll 2
        for (int cb = 0; cb < 8; ++cb) {
            const float4 kv = krow[cb];
            const float4 qv = qrow[cb];
            float kq[4];
            kq[0] = kv.x - qv.x; kq[1] = kv.y - qv.y;
            kq[2] = kv.z - qv.z; kq[3] = kv.w - qv.w;
#pragma unroll
            for (int u4 = 0; u4 < 4; ++u4) {
                const int cc = cb * 4 + u4;
                const float pr2 = sWp2[cc][0] * h0 + sWp2[cc][1] * h1 + sWp2[cc][2] * h2 + sbp2[cc];
                const float wp = kq[u4] + pr2;
                const float hh = fmaxf(sa2[cc] * wp + sc2[cc], 0.f);
                acc0 += sW1[0][cc] * hh;
                acc1 += sW1[1][cc] * hh;
                acc2 += sW1[2][cc] * hh;
                acc3 += sW1[3][cc] * hh;
            }
        }
        *(float4*)(w1out + pid * 4) = make_float4(acc0, acc1, acc2, acc3);
        s[0] += acc0; ss[0] += acc0 * acc0;
        s[1] += acc1; ss[1] += acc1 * acc1;
        s[2] += acc2; ss[2] += acc2 * acc2;
        s[3] += acc3; ss[3] += acc3 * acc3;
    }
#pragma unroll
    for (int o = 32; o > 0; o >>= 1) {
#pragma unroll
        for (int u = 0; u < 4; ++u) { s[u] += __shfl_down(s[u], o); ss[u] += __shfl_down(ss[u], o); }
    }
    __shared__ float red[4][8];
    const int wid = t >> 6, lane = t & 63;
    if (lane == 0) {
#pragma unroll
        for (int u = 0; u < 4; ++u) { red[wid][u] = s[u]; red[wid][4 + u] = ss[u]; }
    }
    __syncthreads();
    if (t < 8) P3[blockIdx.x * 8 + t] = red[0][t] + red[1][t] + red[2][t] + red[3][t];
}

// ---------------------------------------------------------------------------
// K8: logits = relu(bn3(w1)) @ Ww2.T + bww2; softmax over ns;
//     out[i,c] = sum_j (v[idx]+pr2) * wsoft[j, c&3]
// Lane l computes ONE logit (j=l>>2, tq=l&3); softmax via shfl_xor(4/8/16);
// weights redistributed with 8 shfl. h read pre-materialized from pr1.
// ---------------------------------------------------------------------------
template <typename T>
__global__ __launch_bounds__(256) void k_out(
    const int* __restrict__ idx, const float* __restrict__ hbuf,
    const float* __restrict__ v, const float* __restrict__ w1in,
    const T* __restrict__ Wp2, const T* __restrict__ bp2,
    const T* __restrict__ Ww2, const T* __restrict__ bww2,
    const float* __restrict__ coef, T* __restrict__ out,
    const int* __restrict__ flag, const int want)
{
    if (flag[0] != want) return;
    const int t = threadIdx.x;
    const int c = t & 31, pi = t >> 5;
    const int jl = c >> 2, tq = c & 3;   // logit-phase role of this lane
    const int wbase = t & 32;            // wave-half base for absolute-lane shuffles
    float a3[4], c3[4], W2r[4];
#pragma unroll
    for (int u = 0; u < 4; ++u) {
        a3[u] = coef[80 + u]; c3[u] = coef[88 + u];
        W2r[u] = cvt<T>(Ww2[tq * 4 + u]);
    }
    const float b2r = cvt<T>(bww2[tq]);
    const float wA = cvt<T>(Wp2[c * 3 + 0]), wB = cvt<T>(Wp2[c * 3 + 1]), wC = cvt<T>(Wp2[c * 3 + 2]);
    const float bb = cvt<T>(bp2[c]);
    const int base0 = blockIdx.x * 128;           // 128 points per block (2048 blocks)
    for (int it = 0; it < 16; ++it) {
        const int i = base0 + it * 8 + pi;
        // ---- one logit per lane: (j=jl, tq)
        const float4 wv = *(const float4*)(w1in + (i * 8 + jl) * 4);
        float lg = b2r;
        lg += W2r[0] * fmaxf(a3[0] * wv.x + c3[0], 0.f);
        lg += W2r[1] * fmaxf(a3[1] * wv.y + c3[1], 0.f);
        lg += W2r[2] * fmaxf(a3[2] * wv.z + c3[2], 0.f);
        lg += W2r[3] * fmaxf(a3[3] * wv.w + c3[3], 0.f);
        // ---- softmax over j = lanes stride 4 within the 32-lane point group
        float m = lg;
        m = fmaxf(m, __shfl_xor(m, 4));
        m = fmaxf(m, __shfl_xor(m, 8));
        m = fmaxf(m, __shfl_xor(m, 16));
        const float e = __expf(lg - m);
        float sum = e;
        sum += __shfl_xor(sum, 4);
        sum += __shfl_xor(sum, 8);
        sum += __shfl_xor(sum, 16);
        const float wsm = e / sum;
        // ---- weighted neighbor sum (back in (point,c) layout)
        float acc = 0.f;
#pragma unroll
        for (int j = 0; j < 8; ++j) {
            const float wj = __shfl(wsm, wbase + (j << 2) + tq);
            const int pid = i * 8 + j;
            const int nj = idx[pid];
            const float h0 = hbuf[pid * 3 + 0];
            const float h1 = hbuf[pid * 3 + 1];
            const float h2 = hbuf[pid * 3 + 2];
            const float pr2 = wA * h0 + wB * h1 + wC * h2 + bb;
            acc += (v[nj * 32 + c] + pr2) * wj;
        }
        out[i * 32 + c] = f2t<T>(acc);
    }
}

// ---------------------------------------------------------------------------
template <typename T>
static void launch_pipeline(void* const* d_in, void* d_out, float* ws,
                            int* flag, const int want, hipStream_t stream)
{
    const T*   p    = (const T*)d_in[0];
    const T*   x    = (const T*)d_in[1];
    const int* idx  = (const int*)d_in[2];
    const T*   Wq   = (const T*)d_in[3];
    const T*   bq   = (const T*)d_in[4];
    const T*   Wk   = (const T*)d_in[5];
    const T*   bk   = (const T*)d_in[6];
    const T*   Wv   = (const T*)d_in[7];
    const T*   bv   = (const T*)d_in[8];
    const T*   Wp1  = (const T*)d_in[9];
    const T*   bp1  = (const T*)d_in[10];
    const T*   gp   = (const T*)d_in[11];
    const T*   bp   = (const T*)d_in[12];
    const T*   Wp2  = (const T*)d_in[13];
    const T*   bp2  = (const T*)d_in[14];
    const T*   gw1  = (const T*)d_in[15];
    const T*   bw1  = (const T*)d_in[16];
    const T*   Ww1  = (const T*)d_in[17];
    const T*   bww1 = (const T*)d_in[18];
    const T*   gw2  = (const T*)d_in[19];
    const T*   bw2  = (const T*)d_in[20];
    const T*   Ww2  = (const T*)d_in[21];
    const T*   bww2 = (const T*)d_in[22];
    T* out = (T*)d_out;

    // ws layout: [0] flag (+pad), [16..112) coef, [128..) partials, big arrays after 131072
    // P1: GSTAT*16 = 32768 ; P2: P2ROWS*64 = 65536 (atomic) ; P3: GSTAT*8 = 16384
    // total partials = 114688 < 131072-128  -> big-array offsets unchanged.
    float* coef = ws + 16;                    // 96 floats
    float* P1   = ws + 128;
    float* P2   = P1 + GSTAT * 16;
    float* P3   = P2 + P2ROWS * 64;
    float* q    = ws + 131072;                // NPTS*32
    float* k    = q  + (size_t)NPTS * 32;     // NPTS*32
    float* v    = k  + (size_t)NPTS * 32;     // NPTS*32
    float* pr1  = v  + (size_t)NPTS * 32;     // NPAIR*3 (holds h after k_w1)
    float* w1   = pr1 + (size_t)NPAIR * 3;    // NPAIR*4   (total ~160 MB)

    k_qkv<T><<<dim3(2048, 3, 1), 256, 0, stream>>>(x, Wq, bq, Wk, bk, Wv, bv, q, k, v, P2, flag, want);
    k_pr1<T><<<GSTAT, 256, 0, stream>>>(p, idx, Wp1, bp1, pr1, P1, flag, want);
    k_fin<T, 3, 8><<<3, 256, 0, stream>>>(P1, GSTAT, gp, bp, coef + 0, coef + 8, flag, want);
    k_bn2stat<T><<<GSTAT, 256, 0, stream>>>(idx, pr1, q, k, Wp2, bp2, coef, P2, flag, want);
    k_fin<T, 32, 32><<<32, 256, 0, stream>>>(P2, P2ROWS, gw1, bw1, coef + 16, coef + 48, flag, want);
    k_w1<T><<<GSTAT, 256, 0, stream>>>(idx, pr1, q, k, Wp2, bp2, Ww1, bww1, coef, w1, P3, flag, want);
    k_fin<T, 4, 4><<<4, 256, 0, stream>>>(P3, GSTAT, gw2, bw2, coef + 80, coef + 88, flag, want);
    k_out<T><<<2048, 256, 0, stream>>>(idx, pr1, v, w1, Wp2, bp2, Ww2, bww2, coef, out, flag, want);
}

extern "C" void kernel_launch(void* const* d_in, const int* in_sizes, int n_in,
                              void* d_out, int out_size, void* d_ws, size_t ws_size,
                              hipStream_t stream)
{
    float* ws = (float*)d_ws;
    int* flag = (int*)ws;   // ws[0]

    k_detect<<<1, 64, 0, stream>>>((const unsigned int*)d_in[1], flag);
    launch_pipeline<bf16>(d_in, d_out, ws, flag, 0, stream);    // bf16 in -> bf16 out
    launch_pipeline<float>(d_in, d_out, ws, flag, 1, stream);   // fp32 in -> fp32 out
}

// Round 6
// 427.486 us; speedup vs baseline: 1.3612x; 1.3612x over previous
//
#include <hip/hip_runtime.h>
#include <hip/hip_bf16.h>

// Problem constants (from reference): N=262144, NS=8, C=32, S=8 -> C/S=4
#define NPTS   262144
#define NSAMP  8
#define NPAIR  (NPTS * NSAMP)           // 2097152
#define EPSV   1e-5f
#define INVCNT (1.0f / (float)NPAIR)
#define GSTAT  2048                      // grid for stat kernels (8 blocks/CU -> 100% occ ceiling)
#define P2ROWS 1024                      // P2 partial rows (2 blocks atomicAdd per row, fits ws header)

typedef __hip_bfloat16 bf16;

template <typename T> __device__ __forceinline__ float cvt(T v);
template <> __device__ __forceinline__ float cvt<float>(float v) { return v; }
template <> __device__ __forceinline__ float cvt<bf16>(bf16 v) { return __bfloat162float(v); }

template <typename T> __device__ __forceinline__ T f2t(float v);
template <> __device__ __forceinline__ float f2t<float>(float v) { return v; }
template <> __device__ __forceinline__ bf16  f2t<bf16>(float v)  { return __float2bfloat16(v); }

// ---------------------------------------------------------------------------
// Detector: decide whether float inputs are bf16 (flag=0) or fp32 (flag=1).
// ---------------------------------------------------------------------------
__global__ void k_detect(const unsigned int* __restrict__ xw, int* __restrict__ flag)
{
    if (threadIdx.x == 0 && blockIdx.x == 0) {
        int cnt = 0;
        for (int i = 0; i < 256; ++i) {
            const unsigned int w = xw[i];
            const unsigned int e = (w >> 7) & 0xFF;   // exponent of low bf16
            if (e >= 110 && e <= 132) ++cnt;
        }
        flag[0] = (cnt >= 128) ? 0 : 1;
    }
}

// ---------------------------------------------------------------------------
// K1: q,k,v = x @ W.T + b (fp32 out).
// Round-4/5 lesson: per-lane W arrays (32 or 96 floats) get demoted to scratch
// by this compiler in this kernel shape -> GBs of scratch traffic. Revert to
// the round-3 LDS structure (known 88.7us) and cut its DS-throughput cost:
// each thread now accumulates 4 points (stride 8), so each conflict-free
// Wt[.][j][c] b32 read serves 4x the outputs. xs is a 32-point tile read as
// aligned float4 broadcasts. W staging transposes on the GLOBAL read side
// (4KB, L1-hot) so LDS writes are stride-1 conflict-free.
// Also zero-inits the P2 atomic partial rows (runs before k_bn2stat in-stream).
// ---------------------------------------------------------------------------
template <typename T>
__global__ __launch_bounds__(256) void k_qkv(
    const T* __restrict__ x,
    const T* __restrict__ Wq, const T* __restrict__ bq,
    const T* __restrict__ Wk, const T* __restrict__ bk,
    const T* __restrict__ Wv, const T* __restrict__ bv,
    float* __restrict__ q, float* __restrict__ k, float* __restrict__ v,
    float* __restrict__ P2z,
    const int* __restrict__ flag, const int want)
{
    if (flag[0] != want) return;
    __shared__ float Wt[3][32][32];              // [which][j][c]
    __shared__ __align__(16) float xs[32][36];   // 32-point tile, pad 36 (144B rows, 16B-aligned)
    const int t = threadIdx.x;
    // zero P2 partials: 2048 blocks x 32 floats = 65536 = P2ROWS*64
    if (t < 32) P2z[blockIdx.x * 32 + t] = 0.f;
    for (int e = t; e < 1024; e += 256) {
        const int j = e >> 5, c = e & 31;        // LDS write stride-1 in c: conflict-free
        Wt[0][j][c] = cvt<T>(Wq[c * 32 + j]);    // transpose via global read (L1-cached 4KB)
        Wt[1][j][c] = cvt<T>(Wk[c * 32 + j]);
        Wt[2][j][c] = cvt<T>(Wv[c * 32 + j]);
    }
    const int c = t & 31, pg = t >> 5;           // this thread: channel c, points pg+8m
    const float bqv = cvt<T>(bq[c]), bkv = cvt<T>(bk[c]), bvv = cvt<T>(bv[c]);
    const int base0 = blockIdx.x * 128;          // 128 points per block (2048 blocks)
    for (int it = 0; it < 4; ++it) {
        const int pbase = base0 + it * 32;       // 32 points per iteration
        __syncthreads();
        for (int e = t; e < 1024; e += 256)
            xs[e >> 5][e & 31] = cvt<T>(x[(pbase + (e >> 5)) * 32 + (e & 31)]);
        __syncthreads();
        float aq[4], ak[4], av[4];
#pragma unroll
        for (int m = 0; m < 4; ++m) { aq[m] = bqv; ak[m] = bkv; av[m] = bvv; }
#pragma unroll
        for (int j4 = 0; j4 < 8; ++j4) {
            float xr[4][4];
#pragma unroll
            for (int m = 0; m < 4; ++m) {
                const float4 xv = *(const float4*)&xs[pg + 8 * m][j4 * 4];  // broadcast
                xr[m][0] = xv.x; xr[m][1] = xv.y; xr[m][2] = xv.z; xr[m][3] = xv.w;
            }
#pragma unroll
            for (int jj = 0; jj < 4; ++jj) {
                const int j = j4 * 4 + jj;
                const float wq_ = Wt[0][j][c];   // stride-1 across lanes: conflict-free
                const float wk_ = Wt[1][j][c];
                const float wv_ = Wt[2][j][c];
#pragma unroll
                for (int m = 0; m < 4; ++m) {
                    aq[m] += wq_ * xr[m][jj];
                    ak[m] += wk_ * xr[m][jj];
                    av[m] += wv_ * xr[m][jj];
                }
            }
        }
#pragma unroll
        for (int m = 0; m < 4; ++m) {
            const int o = (pbase + pg + 8 * m) * 32 + c;
            q[o] = aq[m]; k[o] = ak[m]; v[o] = av[m];
        }
    }
}

// ---------------------------------------------------------------------------
// K2: pr1 = (p[idx]-p) @ Wp1.T + bp1 (store), BN1 partial sums (3 ch, pad 8)
// Partial row layout: [0..2] sum, [8..10] sumsq, stride 16. 2048 rows.
// ---------------------------------------------------------------------------
template <typename T>
__global__ __launch_bounds__(256) void k_pr1(
    const T* __restrict__ p, const int* __restrict__ idx,
    const T* __restrict__ Wp1, const T* __restrict__ bp1,
    float* __restrict__ pr1, float* __restrict__ P1,
    const int* __restrict__ flag, const int want)
{
    if (flag[0] != want) return;
    float W[3][3], B[3];
#pragma unroll
    for (int a = 0; a < 3; ++a) {
        B[a] = cvt<T>(bp1[a]);
#pragma unroll
        for (int d = 0; d < 3; ++d) W[a][d] = cvt<T>(Wp1[a * 3 + d]);
    }
    const int t = threadIdx.x;
    const int base = blockIdx.x * 1024;           // 1024 pairs per block
    float s[3] = {0.f, 0.f, 0.f}, ss[3] = {0.f, 0.f, 0.f};
    for (int it = 0; it < 1024; it += 256) {
        const int pid = base + it + t;
        const int i = pid >> 3;
        const int nj = idx[pid];
        const float d0 = cvt<T>(p[nj * 3 + 0]) - cvt<T>(p[i * 3 + 0]);
        const float d1 = cvt<T>(p[nj * 3 + 1]) - cvt<T>(p[i * 3 + 1]);
        const float d2 = cvt<T>(p[nj * 3 + 2]) - cvt<T>(p[i * 3 + 2]);
#pragma unroll
        for (int a = 0; a < 3; ++a) {
            const float r = W[a][0] * d0 + W[a][1] * d1 + W[a][2] * d2 + B[a];
            pr1[pid * 3 + a] = r;
            s[a] += r; ss[a] += r * r;
        }
    }
#pragma unroll
    for (int o = 32; o > 0; o >>= 1) {
#pragma unroll
        for (int a = 0; a < 3; ++a) { s[a] += __shfl_down(s[a], o); ss[a] += __shfl_down(ss[a], o); }
    }
    __shared__ float red[4][16];
    const int wid = t >> 6, lane = t & 63;
    if (lane == 0) {
#pragma unroll
        for (int u = 0; u < 16; ++u) red[wid][u] = 0.f;
#pragma unroll
        for (int a = 0; a < 3; ++a) { red[wid][a] = s[a]; red[wid][8 + a] = ss[a]; }
    }
    __syncthreads();
    if (t < 16) P1[blockIdx.x * 16 + t] = red[0][t] + red[1][t] + red[2][t] + red[3][t];
}

// ---------------------------------------------------------------------------
// Finalize: reduce partial rows -> coef a/c.
// One block PER CHANNEL (grid = NC_), 256 threads grid-stride over rows.
// ---------------------------------------------------------------------------
template <typename T, int NC_, int NP_>
__global__ __launch_bounds__(256) void k_fin(
    const float* __restrict__ P, const int nrows,
    const T* __restrict__ g, const T* __restrict__ b,
    float* __restrict__ A, float* __restrict__ Cc,
    const int* __restrict__ flag, const int want)
{
    if (flag[0] != want) return;
    constexpr int COLS = 2 * NP_;
    const int c = blockIdx.x;           // channel (< NC_)
    const int t = threadIdx.x;
    float s = 0.f, ss = 0.f;
    for (int r = t; r < nrows; r += 256) {
        s  += P[r * COLS + c];
        ss += P[r * COLS + NP_ + c];
    }
#pragma unroll
    for (int o = 32; o > 0; o >>= 1) { s += __shfl_down(s, o); ss += __shfl_down(ss, o); }
    __shared__ float rs[4], rss[4];
    if ((t & 63) == 0) { rs[t >> 6] = s; rss[t >> 6] = ss; }
    __syncthreads();
    if (t == 0) {
        s  = rs[0] + rs[1] + rs[2] + rs[3];
        ss = rss[0] + rss[1] + rss[2] + rss[3];
        const float m = s * INVCNT;
        const float var = ss * INVCNT - m * m;
        const float a = cvt<T>(g[c]) * rsqrtf(var + EPSV);
        A[c]  = a;
        Cc[c] = cvt<T>(b[c]) - a * m;
    }
}

// ---------------------------------------------------------------------------
// K4: BN2 partials over w_pre = k[idx] - q + relu(bn1(pr1)) @ Wp2.T + bp2
// Layout: c = t&31 (channel-parallel), 8 pairs per 256-thread iteration.
// Partial row: [c] sum, [32+c] sumsq, stride 64. 1024 rows; pairs of blocks
// atomicAdd into the same row (rows zeroed by k_qkv).
// ---------------------------------------------------------------------------
template <typename T>
__global__ __launch_bounds__(256) void k_bn2stat(
    const int* __restrict__ idx, const float* __restrict__ pr1,
    const float* __restrict__ q, const float* __restrict__ k,
    const T* __restrict__ Wp2, const T* __restrict__ bp2,
    const float* __restrict__ coef, float* __restrict__ P2,
    const int* __restrict__ flag, const int want)
{
    if (flag[0] != want) return;
    const int t = threadIdx.x;
    const int c = t & 31;
    const float a10 = coef[0], a11 = coef[1], a12 = coef[2];
    const float c10 = coef[8], c11 = coef[9], c12 = coef[10];
    const float w0 = cvt<T>(Wp2[c * 3 + 0]), w1 = cvt<T>(Wp2[c * 3 + 1]), w2 = cvt<T>(Wp2[c * 3 + 2]);
    const float bb = cvt<T>(bp2[c]);
    float s = 0.f, ss = 0.f;
    const int base = blockIdx.x * 1024;           // 1024 pairs per block
    for (int it = 0; it < 1024; it += 8) {
        const int pid = base + it + (t >> 5);
        const int i = pid >> 3;
        const int nj = idx[pid];
        const float h0 = fmaxf(a10 * pr1[pid * 3 + 0] + c10, 0.f);
        const float h1 = fmaxf(a11 * pr1[pid * 3 + 1] + c11, 0.f);
        const float h2 = fmaxf(a12 * pr1[pid * 3 + 2] + c12, 0.f);
        const float pr2 = w0 * h0 + w1 * h1 + w2 * h2 + bb;
        const float wp = k[nj * 32 + c] - q[i * 32 + c] + pr2;
        s += wp; ss += wp * wp;
    }
    s += __shfl_down(s, 32); ss += __shfl_down(ss, 32);
    __shared__ float red[4][64];
    const int wid = t >> 6, lane = t & 63;
    if (lane < 32) { red[wid][lane] = s; red[wid][32 + lane] = ss; }
    __syncthreads();
    if (t < 64) atomicAdd(&P2[(blockIdx.x >> 1) * 64 + t],
                          red[0][t] + red[1][t] + red[2][t] + red[3][t]);
}

// ---------------------------------------------------------------------------
// K6: w1 = relu(bn2(w_pre)) @ Ww1.T + bww1 (store), BN3 partials (4 ch)
// Thread-per-pair. Partial row: [0..3] sum, [4..7] sumsq, stride 8. 2048 rows.
// Also writes h = relu(bn1(pr1)) BACK into pr1 in-place (each pid owned by
// exactly one thread; bn2stat already consumed raw pr1) so k_out can skip BN1.
// ---------------------------------------------------------------------------
template <typename T>
__global__ __launch_bounds__(256, 4) void k_w1(
    const int* __restrict__ idx, float* __restrict__ pr1,
    const float* __restrict__ q, const float* __restrict__ k,
    const T* __restrict__ Wp2, const T* __restrict__ bp2,
    const T* __restrict__ Ww1, const T* __restrict__ bww1,
    const float* __restrict__ coef, float* __restrict__ w1out, float* __restrict__ P3,
    const int* __restrict__ flag, const int want)
{
    if (flag[0] != want) return;
    __shared__ float sWp2[32][3], sbp2[32], sW1[4][32], sb1[4], sa2[32], sc2[32];
    const int t = threadIdx.x;
    if (t < 32) {
        sWp2[t][0] = cvt<T>(Wp2[t * 3 + 0]);
        sWp2[t][1] = cvt<T>(Wp2[t * 3 + 1]);
        sWp2[t][2] = cvt<T>(Wp2[t * 3 + 2]);
        sbp2[t] = cvt<T>(bp2[t]);
        sa2[t] = coef[16 + t];
        sc2[t] = coef[48 + t];
    }
    if (t < 4) sb1[t] = cvt<T>(bww1[t]);
    if (t < 128) sW1[t >> 5][t & 31] = cvt<T>(Ww1[t]);
    __syncthreads();
    const float a10 = coef[0], a11 = coef[1], a12 = coef[2];
    const float c10 = coef[8], c11 = coef[9], c12 = coef[10];
    float s[4] = {0.f, 0.f, 0.f, 0.f}, ss[4] = {0.f, 0.f, 0.f, 0.f};
    const int base = blockIdx.x * 1024;           // 1024 pairs per block
    for (int it = 0; it < 1024; it += 256) {
        const int pid = base + it + t;
        const int i = pid >> 3;
        const int nj = idx[pid];
        const float h0 = fmaxf(a10 * pr1[pid * 3 + 0] + c10, 0.f);
        const float h1 = fmaxf(a11 * pr1[pid * 3 + 1] + c11, 0.f);
        const float h2 = fmaxf(a12 * pr1[pid * 3 + 2] + c12, 0.f);
        pr1[pid * 3 + 0] = h0;          // materialize h for k_out
        pr1[pid * 3 + 1] = h1;
        pr1[pid * 3 + 2] = h2;
        float acc0 = sb1[0], acc1 = sb1[1], acc2 = sb1[2], acc3 = sb1[3];
        const float4* __restrict__ krow = (const float4*)(k + nj * 32);
        const float4* __restrict__ qrow = (const float4*)(q + i * 32);
#pragma unroll 2
        for (int cb = 0; cb < 8; ++cb) {
            const float4 kv = krow[cb];
            const float4 qv = qrow[cb];
            float kq[4];
            kq[0] = kv.x - qv.x; kq[1] = kv.y - qv.y;
            kq[2] = kv.z - qv.z; kq[3] = kv.w - qv.w;
#pragma unroll
            for (int u4 = 0; u4 < 4; ++u4) {
                const int cc = cb * 4 + u4;
                const float pr2 = sWp2[cc][0] * h0 + sWp2[cc][1] * h1 + sWp2[cc][2] * h2 + sbp2[cc];
                const float wp = kq[u4] + pr2;
                const float hh = fmaxf(sa2[cc] * wp + sc2[cc], 0.f);
                acc0 += sW1[0][cc] * hh;
                acc1 += sW1[1][cc] * hh;
                acc2 += sW1[2][cc] * hh;
                acc3 += sW1[3][cc] * hh;
            }
        }
        *(float4*)(w1out + pid * 4) = make_float4(acc0, acc1, acc2, acc3);
        s[0] += acc0; ss[0] += acc0 * acc0;
        s[1] += acc1; ss[1] += acc1 * acc1;
        s[2] += acc2; ss[2] += acc2 * acc2;
        s[3] += acc3; ss[3] += acc3 * acc3;
    }
#pragma unroll
    for (int o = 32; o > 0; o >>= 1) {
#pragma unroll
        for (int u = 0; u < 4; ++u) { s[u] += __shfl_down(s[u], o); ss[u] += __shfl_down(ss[u], o); }
    }
    __shared__ float red[4][8];
    const int wid = t >> 6, lane = t & 63;
    if (lane == 0) {
#pragma unroll
        for (int u = 0; u < 4; ++u) { red[wid][u] = s[u]; red[wid][4 + u] = ss[u]; }
    }
    __syncthreads();
    if (t < 8) P3[blockIdx.x * 8 + t] = red[0][t] + red[1][t] + red[2][t] + red[3][t];
}

// ---------------------------------------------------------------------------
// K8: logits = relu(bn3(w1)) @ Ww2.T + bww2; softmax over ns;
//     out[i,c] = sum_j (v[idx]+pr2) * wsoft[j, c&3]
// Lane l computes ONE logit (j=l>>2, tq=l&3); softmax via shfl_xor(4/8/16);
// weights redistributed with 8 shfl. h read pre-materialized from pr1.
// ---------------------------------------------------------------------------
template <typename T>
__global__ __launch_bounds__(256) void k_out(
    const int* __restrict__ idx, const float* __restrict__ hbuf,
    const float* __restrict__ v, const float* __restrict__ w1in,
    const T* __restrict__ Wp2, const T* __restrict__ bp2,
    const T* __restrict__ Ww2, const T* __restrict__ bww2,
    const float* __restrict__ coef, T* __restrict__ out,
    const int* __restrict__ flag, const int want)
{
    if (flag[0] != want) return;
    const int t = threadIdx.x;
    const int c = t & 31, pi = t >> 5;
    const int jl = c >> 2, tq = c & 3;   // logit-phase role of this lane
    const int wbase = t & 32;            // wave-half base for absolute-lane shuffles
    float a3[4], c3[4], W2r[4];
#pragma unroll
    for (int u = 0; u < 4; ++u) {
        a3[u] = coef[80 + u]; c3[u] = coef[88 + u];
        W2r[u] = cvt<T>(Ww2[tq * 4 + u]);
    }
    const float b2r = cvt<T>(bww2[tq]);
    const float wA = cvt<T>(Wp2[c * 3 + 0]), wB = cvt<T>(Wp2[c * 3 + 1]), wC = cvt<T>(Wp2[c * 3 + 2]);
    const float bb = cvt<T>(bp2[c]);
    const int base0 = blockIdx.x * 128;           // 128 points per block (2048 blocks)
    for (int it = 0; it < 16; ++it) {
        const int i = base0 + it * 8 + pi;
        // ---- one logit per lane: (j=jl, tq)
        const float4 wv = *(const float4*)(w1in + (i * 8 + jl) * 4);
        float lg = b2r;
        lg += W2r[0] * fmaxf(a3[0] * wv.x + c3[0], 0.f);
        lg += W2r[1] * fmaxf(a3[1] * wv.y + c3[1], 0.f);
        lg += W2r[2] * fmaxf(a3[2] * wv.z + c3[2], 0.f);
        lg += W2r[3] * fmaxf(a3[3] * wv.w + c3[3], 0.f);
        // ---- softmax over j = lanes stride 4 within the 32-lane point group
        float m = lg;
        m = fmaxf(m, __shfl_xor(m, 4));
        m = fmaxf(m, __shfl_xor(m, 8));
        m = fmaxf(m, __shfl_xor(m, 16));
        const float e = __expf(lg - m);
        float sum = e;
        sum += __shfl_xor(sum, 4);
        sum += __shfl_xor(sum, 8);
        sum += __shfl_xor(sum, 16);
        const float wsm = e / sum;
        // ---- weighted neighbor sum (back in (point,c) layout)
        float acc = 0.f;
#pragma unroll
        for (int j = 0; j < 8; ++j) {
            const float wj = __shfl(wsm, wbase + (j << 2) + tq);
            const int pid = i * 8 + j;
            const int nj = idx[pid];
            const float h0 = hbuf[pid * 3 + 0];
            const float h1 = hbuf[pid * 3 + 1];
            const float h2 = hbuf[pid * 3 + 2];
            const float pr2 = wA * h0 + wB * h1 + wC * h2 + bb;
            acc += (v[nj * 32 + c] + pr2) * wj;
        }
        out[i * 32 + c] = f2t<T>(acc);
    }
}

// ---------------------------------------------------------------------------
template <typename T>
static void launch_pipeline(void* const* d_in, void* d_out, float* ws,
                            int* flag, const int want, hipStream_t stream)
{
    const T*   p    = (const T*)d_in[0];
    const T*   x    = (const T*)d_in[1];
    const int* idx  = (const int*)d_in[2];
    const T*   Wq   = (const T*)d_in[3];
    const T*   bq   = (const T*)d_in[4];
    const T*   Wk   = (const T*)d_in[5];
    const T*   bk   = (const T*)d_in[6];
    const T*   Wv   = (const T*)d_in[7];
    const T*   bv   = (const T*)d_in[8];
    const T*   Wp1  = (const T*)d_in[9];
    const T*   bp1  = (const T*)d_in[10];
    const T*   gp   = (const T*)d_in[11];
    const T*   bp   = (const T*)d_in[12];
    const T*   Wp2  = (const T*)d_in[13];
    const T*   bp2  = (const T*)d_in[14];
    const T*   gw1  = (const T*)d_in[15];
    const T*   bw1  = (const T*)d_in[16];
    const T*   Ww1  = (const T*)d_in[17];
    const T*   bww1 = (const T*)d_in[18];
    const T*   gw2  = (const T*)d_in[19];
    const T*   bw2  = (const T*)d_in[20];
    const T*   Ww2  = (const T*)d_in[21];
    const T*   bww2 = (const T*)d_in[22];
    T* out = (T*)d_out;

    // ws layout: [0] flag (+pad), [16..112) coef, [128..) partials, big arrays after 131072
    // P1: GSTAT*16 = 32768 ; P2: P2ROWS*64 = 65536 (atomic) ; P3: GSTAT*8 = 16384
    // total partials = 114688 < 131072-128  -> big-array offsets unchanged.
    float* coef = ws + 16;                    // 96 floats
    float* P1   = ws + 128;
    float* P2   = P1 + GSTAT * 16;
    float* P3   = P2 + P2ROWS * 64;
    float* q    = ws + 131072;                // NPTS*32
    float* k    = q  + (size_t)NPTS * 32;     // NPTS*32
    float* v    = k  + (size_t)NPTS * 32;     // NPTS*32
    float* pr1  = v  + (size_t)NPTS * 32;     // NPAIR*3 (holds h after k_w1)
    float* w1   = pr1 + (size_t)NPAIR * 3;    // NPAIR*4   (total ~160 MB)

    k_qkv<T><<<2048, 256, 0, stream>>>(x, Wq, bq, Wk, bk, Wv, bv, q, k, v, P2, flag, want);
    k_pr1<T><<<GSTAT, 256, 0, stream>>>(p, idx, Wp1, bp1, pr1, P1, flag, want);
    k_fin<T, 3, 8><<<3, 256, 0, stream>>>(P1, GSTAT, gp, bp, coef + 0, coef + 8, flag, want);
    k_bn2stat<T><<<GSTAT, 256, 0, stream>>>(idx, pr1, q, k, Wp2, bp2, coef, P2, flag, want);
    k_fin<T, 32, 32><<<32, 256, 0, stream>>>(P2, P2ROWS, gw1, bw1, coef + 16, coef + 48, flag, want);
    k_w1<T><<<GSTAT, 256, 0, stream>>>(idx, pr1, q, k, Wp2, bp2, Ww1, bww1, coef, w1, P3, flag, want);
    k_fin<T, 4, 4><<<4, 256, 0, stream>>>(P3, GSTAT, gw2, bw2, coef + 80, coef + 88, flag, want);
    k_out<T><<<2048, 256, 0, stream>>>(idx, pr1, v, w1, Wp2, bp2, Ww2, bww2, coef, out, flag, want);
}

extern "C" void kernel_launch(void* const* d_in, const int* in_sizes, int n_in,
                              void* d_out, int out_size, void* d_ws, size_t ws_size,
                              hipStream_t stream)
{
    float* ws = (float*)d_ws;
    int* flag = (int*)ws;   // ws[0]

    k_detect<<<1, 64, 0, stream>>>((const unsigned int*)d_in[1], flag);
    launch_pipeline<bf16>(d_in, d_out, ws, flag, 0, stream);    // bf16 in -> bf16 out
    launch_pipeline<float>(d_in, d_out, ws, flag, 1, stream);   // fp32 in -> fp32 out
}